// Round 7
// baseline (346.335 us; speedup 1.0000x reference)
//
#include <hip/hip_runtime.h>
#include <stdint.h>

typedef __attribute__((ext_vector_type(8))) short bf16x8;
typedef __attribute__((ext_vector_type(4))) float f32x4;

#define N_IMG 32
#define CI 256
#define CO 256
#define HH_ 56
#define WW_ 56
#define HP 58
#define WP 58
#define SPP (HP*WP)   /* 3364 padded spatial */
#define SPI (HH_*WW_) /* 3136 */

#define XB_BYTES ((size_t)N_IMG*SPP*CI*2)   /* 55,115,776 */
#define W2_OFF   XB_BYTES
#define W2_BYTES ((size_t)9*CO*CI*2)        /* 1,179,648 */
#define SCALE_OFF (W2_OFF + W2_BYTES)

__device__ __forceinline__ unsigned int pack_bf16(float a, float b) {
  unsigned int u0 = __builtin_bit_cast(unsigned int, a);
  unsigned int u1 = __builtin_bit_cast(unsigned int, b);
  u0 = (u0 + 0x7fffu + ((u0 >> 16) & 1u)) >> 16;   // RNE f32->bf16
  u1 = (u1 + 0x7fffu + ((u1 >> 16) & 1u)) >> 16;
  return u0 | (u1 << 16);
}

__device__ __forceinline__ void gl_lds16(const void* g, void* l) {
  __builtin_amdgcn_global_load_lds(
      (const __attribute__((address_space(1))) unsigned int*)g,
      (__attribute__((address_space(3))) unsigned int*)l, 16, 0, 0);
}

// ---------------- prep 1: zero ONLY the pad border of xb ----------------
// border cells per n: 2*58 + 2*56 = 228; each 256c*2B = 512B = 32 chunks of 16B
// total threads = 32n * 228 * 32 = 233,472 = 912 blocks * 256
__global__ __launch_bounds__(256) void border_zero_k(unsigned short* __restrict__ xb) {
  int gid = blockIdx.x*256 + threadIdx.x;
  int cell = gid >> 5, part = gid & 31;
  int n = cell / 228, b = cell - n*228;
  int h, w;
  if (b < 58)       { h = 0;          w = b;        }
  else if (b < 116) { h = 57;         w = b - 58;   }
  else if (b < 172) { h = b - 116 + 1; w = 0;       }
  else              { h = b - 172 + 1; w = 57;      }
  uint4 z = make_uint4(0u,0u,0u,0u);
  *(uint4*)&xb[((size_t)n*SPP + (size_t)h*WP + w)*CI + part*8] = z;
}

// ---------------- prep 2: NCHW fp32 -> padded NHWC bf16 ----------------
// block = (n, cb: 64-channel group, spt: 64-pixel tile). LDS fp32 [64sp][64c],
// XOR-swizzled columns so the transpose-read is b128 with ~2-way conflicts.
__global__ __launch_bounds__(256) void nchw2nhwc_k(const float* __restrict__ x,
                                                   unsigned short* __restrict__ xb) {
  __shared__ float tile[64*64];
  int bid = blockIdx.x;
  int n = bid / 196; int r = bid - n*196;      // 196 = 4 cb * 49 tiles
  int cb = r / 49;   int t0 = (r - cb*49) * 64;
  int t = threadIdx.x;
  int row = t >> 4, l16 = t & 15;
  const float* src = x + ((size_t)(n*CI + cb*64))*SPI + t0;
#pragma unroll
  for (int it = 0; it < 4; ++it) {
    int c = it*16 + row;
    float4 v = *(const float4*)&src[(size_t)c*SPI + l16*4];
    const float* vf = (const float*)&v;
#pragma unroll
    for (int j = 0; j < 4; ++j) {
      int sp = l16*4 + j;
      int cs = c ^ (((sp >> 2) & 7) << 3);     // swizzle c bits 3..5 by sp bits 2..4
      tile[sp*64 + cs] = vf[j];
    }
  }
  __syncthreads();
#pragma unroll
  for (int it = 0; it < 2; ++it) {
    int u = it*256 + t;
    int sp = u >> 3, part = u & 7;
    int g = (part*8) ^ (((sp >> 2) & 7) << 3); // 8-aligned group survives XOR
    float4 f0 = *(const float4*)&tile[sp*64 + g];
    float4 f1 = *(const float4*)&tile[sp*64 + g + 4];
    const float* a0 = (const float*)&f0; const float* a1 = (const float*)&f1;
    uint4 pk;
    pk.x = pack_bf16(a0[0], a0[1]);
    pk.y = pack_bf16(a0[2], a0[3]);
    pk.z = pack_bf16(a1[0], a1[1]);
    pk.w = pack_bf16(a1[2], a1[3]);
    int spg = t0 + sp; int h = spg / 56; int w = spg - h*56;
    size_t psp = (size_t)(h+1)*WP + (w+1);
    *(uint4*)&xb[((size_t)n*SPP + psp)*CI + cb*64 + part*8] = pk;
  }
}

// ---------------- prep 3: scale[o]=mean|w|; W2[tap][o][c]=bf16(sign(w)) ----
// thread t = input channel c -> coalesced 2B stores (128B/wave per tap)
__global__ __launch_bounds__(256) void prep_w_k(const float* __restrict__ wt,
                                                unsigned short* __restrict__ w2,
                                                float* __restrict__ scale) {
  int o = blockIdx.x; int t = threadIdx.x;
  const float* wr = wt + (size_t)o*2304 + t*9;  // 9 contiguous taps for channel t
  float s = 0.f;
#pragma unroll
  for (int tap = 0; tap < 9; ++tap) {
    float v = wr[tap];
    s += fabsf(v);
    unsigned short sg = (v > 0.f) ? (unsigned short)0x3F80u
                       : ((v < 0.f) ? (unsigned short)0xBF80u : (unsigned short)0u);
    w2[((size_t)tap*CO + o)*CI + t] = sg;
  }
  __shared__ float red[4];
#pragma unroll
  for (int off = 32; off > 0; off >>= 1) s += __shfl_down(s, off, 64);
  if ((t & 63) == 0) red[t >> 6] = s;
  __syncthreads();
  if (t == 0) scale[o] = (red[0]+red[1]+red[2]+red[3]) * (1.0f/2304.0f);
}

// ---------------- main: implicit-GEMM MFMA conv ----------------
// block: 128 o x 224 px (8h x 28w); 4 waves = 2(o) x 2(px); wave: 64o x 112px
// A (weights) read directly from global (L2-resident, 1.18 MB total).
// B (x patch) double-buffered in LDS, staged via global_load_lds width 16.
// Patch per cc-chunk: [10h][30w][32c] linear = 1200 chunks of 16B.
#define PCH 1280
__global__ __launch_bounds__(256, 2) void binconv_k(
    const unsigned short* __restrict__ xb,
    const unsigned short* __restrict__ w2,
    const float* __restrict__ scale,
    float* __restrict__ out) {
  __shared__ unsigned short sp_buf[2][PCH*8];

  int bid = blockIdx.x;
  int orig = (bid & 7)*112 + (bid >> 3);       // XCD-chunked swizzle (896 % 8 == 0)
  int ot = orig & 1, pt = orig >> 1;
  int n = pt / 14, rem = pt - n*14;            // 14 = 7 h-tiles * 2 w-tiles
  int ht = rem >> 1, wtl = rem & 1;
  int h0 = ht*8, w0 = wtl*28, OB = ot*128;
  int tid = threadIdx.x;
  int lane = tid & 63, wid = tid >> 6;
  int wo = wid >> 1, wp = wid & 1;
  int lrow = lane & 15, lgrp = lane >> 4;

  // per-lane B-fragment bases into patch (tap adds (dh*30+dw)*32)
  int pb[7];
#pragma unroll
  for (int f = 0; f < 7; ++f) {
    int p = wp*112 + f*16 + lrow;
    int th = p / 28; int tw = p - th*28;
    pb[f] = (th*30 + tw)*32 + lgrp*8;
  }

  // per-lane A base: w2[(tap*256 + OB + wo*64 + m*16 + lrow)*256 + cc*32 + lgrp*8]
  const unsigned short* wA = w2 + (((size_t)(OB + wo*64 + lrow)) << 8) + lgrp*8;

  const unsigned short* xsrc = xb + ((size_t)n*SPP + (size_t)h0*WP + w0)*CI;

  f32x4 acc[4][7];
#pragma unroll
  for (int m = 0; m < 4; ++m)
#pragma unroll
    for (int f = 0; f < 7; ++f) {
      f32x4 z = {0.f, 0.f, 0.f, 0.f};
      acc[m][f] = z;
    }

#define STAGE(BUF, CC)                                                        \
  {                                                                           \
    const unsigned short* g_ = xsrc + (CC)*32;                                \
    _Pragma("unroll")                                                         \
    for (int rdi = 0; rdi < 5; ++rdi) {                                       \
      int u = rdi*256 + tid;                                                  \
      if (u < 1200) {                                                         \
        int rr = u >> 2, cg = u & 3;                                          \
        int hh = rr / 30, ww = rr - hh*30;                                    \
        gl_lds16(g_ + ((size_t)hh*WP + ww)*CI + cg*8,                         \
                 &sp_buf[BUF][(size_t)(rdi*256 + (tid & ~63))*8]);            \
      }                                                                       \
    }                                                                         \
  }

  STAGE(0, 0);
  __syncthreads();

  for (int cc = 0; cc < 8; ++cc) {
    int cur = cc & 1;
    if (cc < 7) STAGE(cur ^ 1, cc + 1);        // overlaps with compute below

    const unsigned short* aCC = wA + cc*32;
#pragma unroll
    for (int tap = 0; tap < 9; ++tap) {
      const int dh = tap / 3, dw = tap - dh*3;
      const int toff = (dh*30 + dw)*32;
      const unsigned short* aP = aCC + ((size_t)tap << 16);  // tap*256*256
      bf16x8 a0 = *(const bf16x8*)(aP);
      bf16x8 a1 = *(const bf16x8*)(aP + 4096);               // m*16*256
      bf16x8 a2 = *(const bf16x8*)(aP + 8192);
      bf16x8 a3 = *(const bf16x8*)(aP + 12288);
      bf16x8 bv[7];
#pragma unroll
      for (int f = 0; f < 7; ++f)
        bv[f] = *(const bf16x8*)&sp_buf[cur][pb[f] + toff];
#pragma unroll
      for (int f = 0; f < 7; ++f) {
        acc[0][f] = __builtin_amdgcn_mfma_f32_16x16x32_bf16(a0, bv[f], acc[0][f], 0, 0, 0);
        acc[1][f] = __builtin_amdgcn_mfma_f32_16x16x32_bf16(a1, bv[f], acc[1][f], 0, 0, 0);
        acc[2][f] = __builtin_amdgcn_mfma_f32_16x16x32_bf16(a2, bv[f], acc[2][f], 0, 0, 0);
        acc[3][f] = __builtin_amdgcn_mfma_f32_16x16x32_bf16(a3, bv[f], acc[3][f], 0, 0, 0);
      }
    }
    __syncthreads();
  }

  // epilogue: scale (fp32) + store NCHW
  float sc[4][4];
#pragma unroll
  for (int m = 0; m < 4; ++m)
#pragma unroll
    for (int r = 0; r < 4; ++r)
      sc[m][r] = scale[OB + wo*64 + m*16 + lgrp*4 + r];

#pragma unroll
  for (int f = 0; f < 7; ++f) {
    int p = wp*112 + f*16 + lrow;
    int th = p / 28; int tw = p - th*28;
    size_t spo = (size_t)(h0+th)*WW_ + (w0+tw);
#pragma unroll
    for (int m = 0; m < 4; ++m) {
      int o = OB + wo*64 + m*16 + lgrp*4;
      float* dst = out + ((size_t)n*CO + o)*SPI + spo;
#pragma unroll
      for (int r = 0; r < 4; ++r)
        dst[(size_t)r*SPI] = acc[m][f][r] * sc[m][r];
    }
  }
}

extern "C" void kernel_launch(void* const* d_in, const int* in_sizes, int n_in,
                              void* d_out, int out_size, void* d_ws, size_t ws_size,
                              hipStream_t stream) {
  const float* x  = (const float*)d_in[0];
  const float* wt = (const float*)d_in[1];
  float* out = (float*)d_out;
  unsigned short* xb = (unsigned short*)d_ws;
  unsigned short* w2 = (unsigned short*)((char*)d_ws + W2_OFF);
  float* scale = (float*)((char*)d_ws + SCALE_OFF);

  border_zero_k<<<912, 256, 0, stream>>>(xb);
  nchw2nhwc_k<<<6272, 256, 0, stream>>>(x, xb);     // 32n * 4cb * 49 tiles
  prep_w_k<<<256, 256, 0, stream>>>(wt, w2, scale);
  binconv_k<<<896, 256, 0, stream>>>(xb, w2, scale, out);  // 448 px-tiles * 2 o-tiles
}